// Round 5
// baseline (929.807 us; speedup 1.0000x reference)
//
#include <hip/hip_runtime.h>

// SparseConv3d(32->64, k=3, s=2, p=1), (21,800,704) grid, nnz=220939.
// Round 9: dense-map GATHER — r8 with the tile-store bug fixed.
//   r8 post-mortem: zero/store phases covered only 512 of 2048 float4 of
//   the LDS tile (dropped the r<8 loop) -> 3/4 of each output tile never
//   written -> absmax 2.66. Algorithm itself audits clean.
//
//   prep      : zero map (int4), transpose W -> WT[27][64][32], dupcnt=0
//   build_map : map[voxel] = point id via atomicExch; displaced ids (coord
//               duplicates, ~2K expected) appended to duplist
//   gather    : block = 128 output sites (32KB LDS tile). wave owns 32
//               sites; lane = cout. Dual-k probe (low/high half-wave)
//               prefetched 1 round ahead; ballot -> hits; per hit: 8
//               uniform b128 feat loads + 16 v_pk_fma + 1 ds_add.
//               Tile stored once, coalesced (covers zeroing).
//   fixup_dups: displaced points re-scattered with global atomics (exact).

#define CIN    32
#define COUT   64
#define IXD    21
#define IYD    800
#define IZD    704
#define OXD    11
#define OYD    400
#define OZD    352
#define NOUT   (OXD * OYD * OZD)        // 1,548,800
#define NVOX   (IXD * IYD * IZD)        // 11,827,200
#define NVOX4  (NVOX / 4)               // 2,956,800 (exact)
#define BSITES 128
#define NBLK   (NOUT / BSITES)          // 12,100 (exact)
#define NWT    (27 * COUT * CIN)        // 55,296 floats
#define DUPCAP 48000                    // fits known-safe 47.72MB ws budget

typedef float v2f __attribute__((ext_vector_type(2)));

// ---------------------------------------------------------------- prep ----
__global__ __launch_bounds__(256) void prep(const float* __restrict__ w,
                                            int4* __restrict__ map4,
                                            float* __restrict__ wt,
                                            int* __restrict__ dupcnt) {
    const int i = blockIdx.x * 256 + threadIdx.x;
    if (i < NVOX4) map4[i] = make_int4(-1, -1, -1, -1);
    if (i < NWT) {
        const int k  = i >> 11;          // 2048 = 64*32 per offset
        const int rm = i & 2047;
        const int co = rm >> 5;
        const int ci = rm & 31;
        wt[i] = w[k * (CIN * COUT) + ci * COUT + co];   // WT[k][co][ci]
    }
    if (i == 0) *dupcnt = 0;
}

// ----------------------------------------------------------- build_map ----
__global__ __launch_bounds__(256) void build_map(
    const int* __restrict__ coords,
    int* __restrict__ map,
    int* __restrict__ dupcnt,
    int* __restrict__ duplist,
    int nnz)
{
    const int n = blockIdx.x * 256 + threadIdx.x;
    if (n >= nnz) return;
    const int cx = coords[3 * n + 0];
    const int cy = coords[3 * n + 1];
    const int cz = coords[3 * n + 2];
    const int v  = (cx * IYD + cy) * IZD + cz;
    const int old = atomicExch(&map[v], n);
    if (old >= 0) {                       // displaced point: handle in fixup
        const int s = atomicAdd(dupcnt, 1);
        if (s < DUPCAP) duplist[s] = old;
    }
}

// -------------------------------------------------------------- gather ----
__global__ __launch_bounds__(256, 4) void spconv_gather(
    const float* __restrict__ feat,
    const float* __restrict__ wt,
    const int*   __restrict__ map,
    float*       __restrict__ out)
{
    __shared__ float tile[BSITES][COUT];   // 32 KB == output tile

    const int t    = threadIdx.x;
    const int lane = t & 63;
    const int wid  = t >> 6;

    // zero ENTIRE tile (2048 float4) — covers output zeroing
    float4* t4 = (float4*)&tile[0][0];
    #pragma unroll
    for (int r = 0; r < 8; ++r) t4[t + r * 256] = make_float4(0.f, 0.f, 0.f, 0.f);
    __syncthreads();

    // my site (per lane-group of 32): fixed for the whole kernel
    const int ls   = lane & 31;
    const int site = blockIdx.x * BSITES + wid * 32 + ls;
    const int ox   = site / (OYD * OZD);
    const int r0   = site - ox * (OYD * OZD);
    const int oy   = r0 / OZD;
    const int oz   = r0 - oy * OZD;
    const int ix0  = 2 * ox - 1;
    const int iy0  = 2 * oy - 1;
    const int iz0  = 2 * oz - 1;
    const int kh   = lane >> 5;            // low half probes k, high half k+1

    // probe map for kernel offset (kp + kh); -1 if OOB/invalid
    auto probe = [&](int kp) -> int {
        const int kk = kp + kh;
        if (kk >= 27) return -1;
        const int kx = kk / 9;
        const int kr = kk - kx * 9;
        const int ky = kr / 3;
        const int kz = kr - ky * 3;
        const int ix = ix0 + kx, iy = iy0 + ky, iz = iz0 + kz;
        if ((unsigned)ix >= IXD || (unsigned)iy >= IYD || (unsigned)iz >= IZD)
            return -1;
        return map[(ix * IYD + iy) * IZD + iz];
    };

    int v = probe(0);
    for (int kp = 0; kp < 27; kp += 2) {
        const int vnext = (kp + 2 < 27) ? probe(kp + 2) : -1;   // prefetch
        const unsigned long long bal = __ballot(v >= 0);
        #pragma unroll
        for (int s = 0; s < 2; ++s) {
            const int k = kp + s;
            if (k >= 27) break;
            unsigned mask = (unsigned)(bal >> (32 * s));
            if (mask == 0) continue;
            // weight column for k, once per (wave, k-with-hits): 8 x b128
            float4 wv[8];
            const float4* __restrict__ wp =
                (const float4*)(wt + ((size_t)k * COUT + lane) * CIN);
            #pragma unroll
            for (int b = 0; b < 8; ++b) wv[b] = wp[b];
            do {
                const int bit = __builtin_ctz(mask);
                mask &= mask - 1;
                const int p = __builtin_amdgcn_readlane(v, 32 * s + bit);
                // wave-uniform feat row: 8 independent b128 broadcasts
                const float4* __restrict__ fr4 =
                    (const float4*)(feat + (size_t)p * CIN);
                float4 fr[8];
                #pragma unroll
                for (int b = 0; b < 8; ++b) fr[b] = fr4[b];
                v2f a0 = {0.f, 0.f}, a1 = {0.f, 0.f};
                #pragma unroll
                for (int b = 0; b < 8; ++b) {
                    v2f f01 = {fr[b].x, fr[b].y}, f23 = {fr[b].z, fr[b].w};
                    v2f w01 = {wv[b].x, wv[b].y}, w23 = {wv[b].z, wv[b].w};
#if __has_builtin(__builtin_elementwise_fma)
                    a0 = __builtin_elementwise_fma(f01, w01, a0);
                    a1 = __builtin_elementwise_fma(f23, w23, a1);
#else
                    a0[0] = fmaf(f01[0], w01[0], a0[0]);
                    a0[1] = fmaf(f01[1], w01[1], a0[1]);
                    a1[0] = fmaf(f23[0], w23[0], a1[0]);
                    a1[1] = fmaf(f23[1], w23[1], a1[1]);
#endif
                }
                // site owned by this wave; rows partitioned by wid -> ds_add
                atomicAdd(&tile[wid * 32 + bit][lane],
                          (a0[0] + a0[1]) + (a1[0] + a1[1]));
            } while (mask);
        }
        v = vnext;
    }
    __syncthreads();

    // single coalesced 32KB store (ALL 2048 float4) — write-once output
    float4* __restrict__ o4 = (float4*)(out + (size_t)blockIdx.x * (BSITES * COUT));
    #pragma unroll
    for (int r = 0; r < 8; ++r) o4[t + r * 256] = t4[t + r * 256];
}

// ---------------------------------------------------------- fixup_dups ----
__global__ __launch_bounds__(256) void fixup_dups(
    const float* __restrict__ feat,
    const float* __restrict__ wt,
    const int*   __restrict__ coords,
    const int*   __restrict__ duplist,
    const int*   __restrict__ dupcnt,
    float*       __restrict__ out)
{
    const int lane = threadIdx.x & 63;
    const int gw   = blockIdx.x * 4 + (threadIdx.x >> 6);
    const int n    = min(*dupcnt, DUPCAP);
    for (int e = gw; e < n; e += 64 * 4) {
        const int p  = duplist[e];
        const int cx = coords[3 * p + 0];
        const int cy = coords[3 * p + 1];
        const int cz = coords[3 * p + 2];
        int kxl[2], oxl[2], nx;
        int kyl[2], oyl[2], ny;
        int kzl[2], ozl[2], nz;
        {
            const int c1 = cx + 1;
            if (c1 & 1) { kxl[0] = 1; oxl[0] = c1 >> 1; nx = 1; }
            else { kxl[0] = 2; oxl[0] = (c1 - 2) >> 1; nx = 1;
                   if ((c1 >> 1) < OXD) { kxl[1] = 0; oxl[1] = c1 >> 1; nx = 2; } }
        }
        {
            const int c1 = cy + 1;
            if (c1 & 1) { kyl[0] = 1; oyl[0] = c1 >> 1; ny = 1; }
            else { kyl[0] = 2; oyl[0] = (c1 - 2) >> 1; ny = 1;
                   if ((c1 >> 1) < OYD) { kyl[1] = 0; oyl[1] = c1 >> 1; ny = 2; } }
        }
        {
            const int c1 = cz + 1;
            if (c1 & 1) { kzl[0] = 1; ozl[0] = c1 >> 1; nz = 1; }
            else { kzl[0] = 2; ozl[0] = (c1 - 2) >> 1; nz = 1;
                   if ((c1 >> 1) < OZD) { kzl[1] = 0; ozl[1] = c1 >> 1; nz = 2; } }
        }
        const float4* __restrict__ fp = (const float4*)(feat + (size_t)p * CIN);
        float4 fr[8];
        #pragma unroll
        for (int b = 0; b < 8; ++b) fr[b] = fp[b];
        for (int ix = 0; ix < nx; ++ix)
            for (int iy = 0; iy < ny; ++iy)
                for (int iz = 0; iz < nz; ++iz) {
                    const int k    = kxl[ix] * 9 + kyl[iy] * 3 + kzl[iz];
                    const int site = (oxl[ix] * OYD + oyl[iy]) * OZD + ozl[iz];
                    const float4* __restrict__ wp =
                        (const float4*)(wt + ((size_t)k * COUT + lane) * CIN);
                    float acc = 0.f;
                    #pragma unroll
                    for (int b = 0; b < 8; ++b) {
                        const float4 f = fr[b];
                        const float4 w = wp[b];
                        acc = fmaf(f.x, w.x, acc);
                        acc = fmaf(f.y, w.y, acc);
                        acc = fmaf(f.z, w.z, acc);
                        acc = fmaf(f.w, w.w, acc);
                    }
                    atomicAdd(out + (size_t)site * COUT + lane, acc);
                }
    }
}

// -------------------------------------------------------------- launch ----
extern "C" void kernel_launch(void* const* d_in, const int* in_sizes, int n_in,
                              void* d_out, int out_size, void* d_ws, size_t ws_size,
                              hipStream_t stream) {
    const float* feat   = (const float*)d_in[0];
    const int*   coords = (const int*)d_in[1];
    const float* weight = (const float*)d_in[2];
    float*       out    = (float*)d_out;
    const int nnz = in_sizes[0] / CIN;            // 220939

    // workspace (47.72 MB total — within the known-safe r4 footprint):
    //   map[NVOX] (47.31MB) | WT[NWT] (216KB) | dupcnt | duplist[DUPCAP]
    int*   map     = (int*)d_ws;
    float* WT      = (float*)(map + NVOX);
    int*   dupcnt  = (int*)(WT + NWT);
    int*   duplist = dupcnt + 4;

    prep<<<(NVOX4 + 255) / 256, 256, 0, stream>>>(weight, (int4*)map, WT, dupcnt);
    build_map<<<(nnz + 255) / 256, 256, 0, stream>>>(coords, map, dupcnt,
                                                     duplist, nnz);
    spconv_gather<<<NBLK, 256, 0, stream>>>(feat, WT, map, out);
    fixup_dups<<<64, 256, 0, stream>>>(feat, WT, coords, duplist, dupcnt, out);
}